// Round 7
// baseline (213.095 us; speedup 1.0000x reference)
//
#include <hip/hip_runtime.h>
#include <hip/hip_bf16.h>

// Positional encoder: per input element e, 20 outputs [sin(x*2^0..9), cos(x*2^0..9)].
// Memory-bound: 24 MB read + 480 MB write. R5: persistent grid (R3-proven,
// 88.2 us) with ONE change: each thread owns a PAIR of adjacent output quads
// (32 B contiguous per iteration) -> 2 independent dwordx4 nontemporal stores
// in flight, half the loop overhead, still a single contiguous global sweep.
// Total threads T divisible by 5 => both quad-phases (2u)%5, (2u+1)%5 are
// loop-invariant => both slot->(scale,offset) tables hoisted.
// cos(2*pi*r) = sin(2*pi*(r+0.25)); 2^d scaling and 0.25 exact in fp32.

#define ENC_BLOCK 256
#define ENC_GRID  1280              // T = 327,680 threads, divisible by 5

__global__ __launch_bounds__(ENC_BLOCK)
void Encoder_65077344469353_kernel(const float* __restrict__ x,
                                   float* __restrict__ out,
                                   int n_elem) {
    typedef float f4 __attribute__((ext_vector_type(4)));
    const unsigned P     = (unsigned)n_elem * 5u / 2u;  // 15,000,000 quad-pairs
    const unsigned T     = ENC_BLOCK * ENC_GRID;        // 327,680
    const unsigned estep = 2u * T / 5u;                 // 131,072 elems per sweep

    const unsigned u  = blockIdx.x * ENC_BLOCK + threadIdx.x;
    const unsigned qa = (2u * u) % 5u;                  // quad phase of quad 2p
    const unsigned qb = (2u * u + 1u) % 5u;             // quad phase of quad 2p+1
    unsigned ea = (2u * u) / 5u;                        // element of quad 2p
    unsigned eb = (2u * u + 1u) / 5u;                   // element of quad 2p+1

    // Hoisted: out[i] = sin(2*pi * fract(x*sc[i] + off[i]))
    float sca[4], offa[4], scb[4], offb[4];
    #pragma unroll
    for (int i = 0; i < 4; ++i) {
        int s, isc, d;
        s = (int)(qa * 4u) + i; isc = (s >= 10); d = s - 10 * isc;
        sca[i]  = __uint_as_float((unsigned)(127 + d) << 23) * 0.15915494309189535f;
        offa[i] = isc ? 0.25f : 0.0f;
        s = (int)(qb * 4u) + i; isc = (s >= 10); d = s - 10 * isc;
        scb[i]  = __uint_as_float((unsigned)(127 + d) << 23) * 0.15915494309189535f;
        offb[i] = isc ? 0.25f : 0.0f;
    }

    f4* __restrict__ out4 = (f4*)out;

    for (unsigned p = u; p < P; p += T, ea += estep, eb += estep) {
        const float xa = x[ea];                         // adjacent/same lines, dedup'd
        const float xb = x[eb];
        f4 oa, ob;
        oa.x = __builtin_amdgcn_sinf(__builtin_amdgcn_fractf(__builtin_fmaf(xa, sca[0], offa[0])));
        oa.y = __builtin_amdgcn_sinf(__builtin_amdgcn_fractf(__builtin_fmaf(xa, sca[1], offa[1])));
        oa.z = __builtin_amdgcn_sinf(__builtin_amdgcn_fractf(__builtin_fmaf(xa, sca[2], offa[2])));
        oa.w = __builtin_amdgcn_sinf(__builtin_amdgcn_fractf(__builtin_fmaf(xa, sca[3], offa[3])));
        ob.x = __builtin_amdgcn_sinf(__builtin_amdgcn_fractf(__builtin_fmaf(xb, scb[0], offb[0])));
        ob.y = __builtin_amdgcn_sinf(__builtin_amdgcn_fractf(__builtin_fmaf(xb, scb[1], offb[1])));
        ob.z = __builtin_amdgcn_sinf(__builtin_amdgcn_fractf(__builtin_fmaf(xb, scb[2], offb[2])));
        ob.w = __builtin_amdgcn_sinf(__builtin_amdgcn_fractf(__builtin_fmaf(xb, scb[3], offb[3])));
        __builtin_nontemporal_store(oa, out4 + 2u * p);        // 32 B contiguous
        __builtin_nontemporal_store(ob, out4 + 2u * p + 1u);   // per thread-iter
    }
}

extern "C" void kernel_launch(void* const* d_in, const int* in_sizes, int n_in,
                              void* d_out, int out_size, void* d_ws, size_t ws_size,
                              hipStream_t stream) {
    const float* x = (const float*)d_in[0];
    float* out = (float*)d_out;
    const int n_elem = in_sizes[0];                     // N*3 = 6,000,000 (even)
    Encoder_65077344469353_kernel<<<dim3(ENC_GRID), dim3(ENC_BLOCK), 0, stream>>>(
        x, out, n_elem);
}

// Round 8
// 96.087 us; speedup vs baseline: 2.2177x; 2.2177x over previous
//
#include <hip/hip_runtime.h>
#include <hip/hip_bf16.h>

// Positional encoder: per input element e, 20 outputs [sin(x*2^0..9), cos(x*2^0..9)].
// Memory-bound: 24 MB read + 480 MB write. R7: R3 structure (88.2 us proven) with
// WAVE-granular unroll x2: wave w owns 128 consecutive quads/iter; lane l stores
// quads base+l and base+64+l -> two FULL-DENSITY 1KB wave-stores, contiguous 2KB
// per wave, single contiguous sweep. (R4's stride-T unroll = distant streams,
// 111us; R5's per-thread-adjacent = broken coalescing, 213us. This is the only
// unroll preserving both lane density and stream adjacency.)
// Phases g%5 and (g+64)%5 are loop-invariant (2T % 5 == 0) => both tables hoisted.
// cos(2*pi*r) = sin(2*pi*(r+0.25)); 2^d scaling and 0.25 exact in fp32.

#define ENC_BLOCK 256
#define ENC_GRID  1280              // T = 327,680 threads; 2T % 5 == 0

__global__ __launch_bounds__(ENC_BLOCK)
void Encoder_65077344469353_kernel(const float* __restrict__ x,
                                   float* __restrict__ out,
                                   int n_elem) {
    typedef float f4 __attribute__((ext_vector_type(4)));
    const unsigned nq    = (unsigned)n_elem * 5u;       // 30,000,000 quads (mod 128 == 0)
    const unsigned T     = ENC_BLOCK * ENC_GRID;        // 327,680
    const unsigned estep = 2u * T / 5u;                 // 131,072 elems per sweep

    const unsigned u = blockIdx.x * ENC_BLOCK + threadIdx.x;
    const unsigned w = u >> 6;                          // wave id
    const unsigned l = u & 63u;                         // lane
    unsigned g0 = w * 128u + l;                         // quad A (wave-dense span)
    // quad B is g0 + 64 (adjacent wave-dense span)

    const unsigned qa = g0 % 5u;                        // loop-invariant
    const unsigned qb = (g0 + 64u) % 5u;                // loop-invariant
    unsigned ea = g0 / 5u;
    unsigned eb = (g0 + 64u) / 5u;

    // Hoisted: out[i] = sin(2*pi * fract(x*sc[i] + off[i]))
    float sca[4], offa[4], scb[4], offb[4];
    #pragma unroll
    for (int i = 0; i < 4; ++i) {
        int s, isc, d;
        s = (int)(qa * 4u) + i; isc = (s >= 10); d = s - 10 * isc;
        sca[i]  = __uint_as_float((unsigned)(127 + d) << 23) * 0.15915494309189535f;
        offa[i] = isc ? 0.25f : 0.0f;
        s = (int)(qb * 4u) + i; isc = (s >= 10); d = s - 10 * isc;
        scb[i]  = __uint_as_float((unsigned)(127 + d) << 23) * 0.15915494309189535f;
        offb[i] = isc ? 0.25f : 0.0f;
    }

    f4* __restrict__ out4 = (f4*)out;

    for (; g0 < nq; g0 += 2u * T, ea += estep, eb += estep) {
        const float xa = x[ea];
        const float xb = x[eb];
        f4 oa, ob;
        oa.x = __builtin_amdgcn_sinf(__builtin_amdgcn_fractf(__builtin_fmaf(xa, sca[0], offa[0])));
        oa.y = __builtin_amdgcn_sinf(__builtin_amdgcn_fractf(__builtin_fmaf(xa, sca[1], offa[1])));
        oa.z = __builtin_amdgcn_sinf(__builtin_amdgcn_fractf(__builtin_fmaf(xa, sca[2], offa[2])));
        oa.w = __builtin_amdgcn_sinf(__builtin_amdgcn_fractf(__builtin_fmaf(xa, sca[3], offa[3])));
        ob.x = __builtin_amdgcn_sinf(__builtin_amdgcn_fractf(__builtin_fmaf(xb, scb[0], offb[0])));
        ob.y = __builtin_amdgcn_sinf(__builtin_amdgcn_fractf(__builtin_fmaf(xb, scb[1], offb[1])));
        ob.z = __builtin_amdgcn_sinf(__builtin_amdgcn_fractf(__builtin_fmaf(xb, scb[2], offb[2])));
        ob.w = __builtin_amdgcn_sinf(__builtin_amdgcn_fractf(__builtin_fmaf(xb, scb[3], offb[3])));
        __builtin_nontemporal_store(oa, out4 + g0);         // dense 1KB wave-store
        __builtin_nontemporal_store(ob, out4 + g0 + 64u);   // adjacent 1KB
    }
}

extern "C" void kernel_launch(void* const* d_in, const int* in_sizes, int n_in,
                              void* d_out, int out_size, void* d_ws, size_t ws_size,
                              hipStream_t stream) {
    const float* x = (const float*)d_in[0];
    float* out = (float*)d_out;
    const int n_elem = in_sizes[0];                     // N*3 = 6,000,000
    Encoder_65077344469353_kernel<<<dim3(ENC_GRID), dim3(ENC_BLOCK), 0, stream>>>(
        x, out, n_elem);
}